// Round 6
// baseline (205.165 us; speedup 1.0000x reference)
//
#include <hip/hip_runtime.h>
#include <math.h>

// Problem constants (GeoFormer.generate_proposal, ScanNet config)
#define BB 4
#define QQ 128
#define NN 50000
#define CC 20
#define ROWS (BB * QQ)          // 512
#define NV4 (NN / 4)            // 12500 f32x4 per row
#define W32 1568                // padded 32-bit words per row (covers 50176 bits)
#define TPB 256                 // pre/gids kernels
#define TPB2 512                // fused kernel: one block per row
#define ITER 25                 // ceil(NV4 / TPB2)
#define THRESH_CNT 50
#define MIN_CLS 4

// Native clang vector types — required for __builtin_nontemporal_store
typedef float f32x4 __attribute__((ext_vector_type(4)));
typedef int   i32x4 __attribute__((ext_vector_type(4)));

// K_PRE: per-class point bitmask classbit[b][c][w]: bit (p%32) of word p/32 =
// (seg_pred[b][p] == c). 0.5 MB, L2-resident; the fused kernel reads 1 bit per
// element instead of re-reading seg 4 B/elem x Q=128 (102.4 MB -> 3.2 MB).
__global__ void k_pre_classbit(const int* __restrict__ seg,
                               unsigned int* __restrict__ classbit) {
    const int b = blockIdx.y;
    const int p = blockIdx.x * TPB + threadIdx.x;     // point id
    const int lane = threadIdx.x & 63;
    const int cl = (p < NN) ? seg[b * NN + p] : -1;
    // first 32-bit word of this wave's 64-point span
    const int w0 = (blockIdx.x * TPB + (threadIdx.x & ~63)) >> 5;
    #pragma unroll
    for (int c = 0; c < CC; ++c) {
        unsigned long long m = __ballot(cl == c);
        if (lane == 0)
            classbit[((size_t)b * CC + c) * W32 + w0]     = (unsigned int)m;
        if (lane == 32)
            classbit[((size_t)b * CC + c) * W32 + w0 + 1] = (unsigned int)(m >> 32);
    }
}

// K_FUSED: one block owns one full row (b,q). Phase 1: argmax (folded in),
// stream the row, keep sel bits in registers (4 VGPRs/thread), block-reduce
// cnt / sum-of-sigmoid. Phase 2 (after one __syncthreads): write the gated
// 0/1 mask straight from registers + the row's scores/valid/cls tail entries.
// No atomics, no intermediate buffers, no second pass over memory.
template <bool USE_BITS>
__global__ __launch_bounds__(TPB2) void k_fused(
        const float* __restrict__ mask_logits,
        const float* __restrict__ cls_logits,
        const int*   __restrict__ seg_pred,
        const unsigned int* __restrict__ classbit,
        float* __restrict__ out) {
    const int row = blockIdx.x;          // 0..511  (b*Q + q)
    const int b   = row >> 7;            // row / Q
    const int tid = threadIdx.x;

    __shared__ float s_logit[CC];
    __shared__ int   s_cls;
    __shared__ float s_on;
    if (tid < CC) s_logit[tid] = cls_logits[row * CC + tid];
    __syncthreads();
    if (tid == 0) {
        // jnp.argmax tie-break = first max (strict '>' forward scan)
        float best = s_logit[0];
        int bi = 0;
        #pragma unroll
        for (int c = 1; c < CC; ++c) {
            if (s_logit[c] > best) { best = s_logit[c]; bi = c; }
        }
        s_cls = bi;
    }
    __syncthreads();
    const int cls = s_cls;

    const f32x4* __restrict__ ml = (const f32x4*)mask_logits + (size_t)row * NV4;
    const unsigned int* __restrict__ cb =
        classbit + ((size_t)b * CC + cls) * W32;
    const i32x4* __restrict__ sp = (const i32x4*)seg_pred + (size_t)b * NV4;

    unsigned int bw[4] = {0u, 0u, 0u, 0u};   // 25 iters x 4 bits = 100 bits
    float lsum = 0.0f;
    int   lcnt = 0;
    #pragma unroll
    for (int it = 0; it < ITER; ++it) {
        const int idx = it * TPB2 + tid;     // idx & 7 == tid & 7
        if (idx < NV4) {
            f32x4 vv = ml[idx];
            unsigned int nib;
            if (USE_BITS) {
                unsigned int cw = cb[idx >> 3];
                nib = (cw >> ((tid & 7) * 4)) & 0xFu;
            } else {
                i32x4 ss = sp[idx];
                nib = ((ss.x == cls) ? 1u : 0u) | ((ss.y == cls) ? 2u : 0u)
                    | ((ss.z == cls) ? 4u : 0u) | ((ss.w == cls) ? 8u : 0u);
            }
            // sigmoid(x) > 0.5  <=>  x > 0
            unsigned int se = ((vv.x > 0.0f) ? 1u : 0u) | ((vv.y > 0.0f) ? 2u : 0u)
                            | ((vv.z > 0.0f) ? 4u : 0u) | ((vv.w > 0.0f) ? 8u : 0u);
            unsigned int sel = se & nib;
            lsum += ((sel & 1u) ? 1.0f / (1.0f + __expf(-vv.x)) : 0.0f)
                  + ((sel & 2u) ? 1.0f / (1.0f + __expf(-vv.y)) : 0.0f)
                  + ((sel & 4u) ? 1.0f / (1.0f + __expf(-vv.z)) : 0.0f)
                  + ((sel & 8u) ? 1.0f / (1.0f + __expf(-vv.w)) : 0.0f);
            lcnt += __popc(sel);
            bw[it >> 3] |= sel << (4 * (it & 7));
        }
    }

    // block reduce: wave64 shuffle then cross-wave via LDS
    #pragma unroll
    for (int off = 32; off > 0; off >>= 1) {
        lsum += __shfl_down(lsum, off);
        lcnt += __shfl_down(lcnt, off);
    }
    __shared__ float ssum[TPB2 / 64];
    __shared__ int   scnt[TPB2 / 64];
    const int wave = tid >> 6;
    const int lane = tid & 63;
    if (lane == 0) { ssum[wave] = lsum; scnt[wave] = lcnt; }
    __syncthreads();
    if (tid == 0) {
        float ts = 0.0f;
        int   tc = 0;
        #pragma unroll
        for (int w = 0; w < TPB2 / 64; ++w) { ts += ssum[w]; tc += scnt[w]; }
        const int valid = (tc >= THRESH_CNT) && (cls >= MIN_CLS);
        float* tail = out + (size_t)ROWS * NN;
        tail[row]            = valid ? (ts / (float)(tc > 1 ? tc : 1)) : 0.0f;
        tail[ROWS + row]     = valid ? 1.0f : 0.0f;
        tail[2 * ROWS + row] = (float)cls;
        s_on = valid ? 1.0f : 0.0f;
    }
    __syncthreads();
    const float on = s_on;

    // Phase 2: gated mask write straight from register bits (NT stores)
    f32x4* __restrict__ om = (f32x4*)out + (size_t)row * NV4;
    #pragma unroll
    for (int it = 0; it < ITER; ++it) {
        const int idx = it * TPB2 + tid;
        if (idx < NV4) {
            const unsigned int nib = (bw[it >> 3] >> (4 * (it & 7))) & 0xFu;
            f32x4 o;
            o.x = (nib & 1u) ? on : 0.0f;
            o.y = (nib & 2u) ? on : 0.0f;
            o.z = (nib & 4u) ? on : 0.0f;
            o.w = (nib & 8u) ? on : 0.0f;
            __builtin_nontemporal_store(o, &om[idx]);
        }
    }
}

// K_GIDS: global_ids = fg_idxs reshaped, int -> float (vectorized, NT).
__global__ void k_gids(const int* __restrict__ fg, float* __restrict__ out) {
    const int idx = blockIdx.x * blockDim.x + threadIdx.x;
    const int nv4 = (BB * NN) / 4;   // 50000
    if (idx < nv4) {
        i32x4 v = ((const i32x4*)fg)[idx];
        f32x4 o;
        o.x = (float)v.x; o.y = (float)v.y; o.z = (float)v.z; o.w = (float)v.w;
        __builtin_nontemporal_store(o, &((f32x4*)out)[idx]);
    }
}

extern "C" void kernel_launch(void* const* d_in, const int* in_sizes, int n_in,
                              void* d_out, int out_size, void* d_ws, size_t ws_size,
                              hipStream_t stream) {
    const float* mask_logits = (const float*)d_in[0];   // [B,Q,N] f32
    const float* cls_logits  = (const float*)d_in[1];   // [B,Q,C] f32
    const int*   seg_pred    = (const int*)d_in[2];     // [B,N]   int
    const int*   fg_idxs     = (const int*)d_in[3];     // [B*N]   int

    float* out = (float*)d_out;
    unsigned int* classbit = (unsigned int*)d_ws;       // 0.5 MB

    // Output layout (flat, return order):
    //   [0, ROWS*NN)  proposal_masks | [+ROWS) scores | [+ROWS) valid
    //   [+ROWS) cls_pred | [+BB*NN) global_ids
    float* out_gids = out + (size_t)ROWS * NN + 3 * ROWS;

    const size_t cb_bytes = (size_t)BB * CC * W32 * sizeof(unsigned int);
    const bool use_bits = (ws_size >= cb_bytes);   // constant across calls

    if (use_bits) {
        dim3 gp((NN + TPB - 1) / TPB, BB);   // (196, 4)
        k_pre_classbit<<<gp, TPB, 0, stream>>>(seg_pred, classbit);
        k_fused<true><<<ROWS, TPB2, 0, stream>>>(
            mask_logits, cls_logits, seg_pred, classbit, out);
    } else {
        k_fused<false><<<ROWS, TPB2, 0, stream>>>(
            mask_logits, cls_logits, seg_pred, classbit, out);
    }

    k_gids<<<((BB * NN) / 4 + TPB - 1) / TPB, TPB, 0, stream>>>(fg_idxs, out_gids);
}

// Round 7
// 202.819 us; speedup vs baseline: 1.0116x; 1.0116x over previous
//
#include <hip/hip_runtime.h>
#include <math.h>

// Problem constants (GeoFormer.generate_proposal, ScanNet config)
#define BB 4
#define QQ 128
#define NN 50000
#define CC 20
#define ROWS (BB * QQ)          // 512
#define NV4 (NN / 4)            // 12500 f32x4 chunks per row
#define TPB 256
#define UNROLL 4
#define BPR 13                  // ceil(12500 / (256*4)) blocks per row
#define W32 1568                // padded 32-bit words per row (covers 50176 bits)
#define THRESH_CNT 50
#define MIN_CLS 4

// Native clang vector types — required for __builtin_nontemporal_store
typedef float f32x4 __attribute__((ext_vector_type(4)));
typedef int   i32x4 __attribute__((ext_vector_type(4)));

// Workspace header (k0 re-inits every call; harness poisons ws with 0xAA).
// Layout: Ws | classbit[BB*CC*W32] (0.50 MB)
struct Ws {
    float sum[ROWS];
    int   cnt[ROWS];
    int   cls[ROWS];
    int   valid[ROWS];
};

// K0: per-(b,q) argmax over C=20 class logits (jnp.argmax tie-break = first
// max, i.e. strict '>' forward scan), and zero the accumulators.
__global__ void k0_argmax_zero(const float* __restrict__ cls_logits, Ws* ws) {
    int r = blockIdx.x * blockDim.x + threadIdx.x;
    if (r >= ROWS) return;
    const float* p = cls_logits + r * CC;
    float best = p[0];
    int bi = 0;
    #pragma unroll
    for (int c = 1; c < CC; ++c) {
        float v = p[c];
        if (v > best) { best = v; bi = c; }
    }
    ws->cls[r] = bi;
    ws->sum[r] = 0.0f;
    ws->cnt[r] = 0;
}

// K_PRE: per-class point bitmask classbit[b][c][w]: bit (p%32) of word p/32 =
// (seg_pred[b][p] == c). 0.5 MB, L2-resident. k1 then reads 1 bit/element
// instead of re-reading seg 4 B/elem x Q=128 (102.4 MB -> ~6 MB requested).
__global__ void k_pre_classbit(const int* __restrict__ seg,
                               unsigned int* __restrict__ classbit) {
    const int b = blockIdx.y;
    const int p = blockIdx.x * TPB + threadIdx.x;     // point id
    const int lane = threadIdx.x & 63;
    const int cl = (p < NN) ? seg[b * NN + p] : -1;
    // first 32-bit word of this wave's 64-point span
    const int w0 = (blockIdx.x * TPB + (threadIdx.x & ~63)) >> 5;
    #pragma unroll
    for (int c = 0; c < CC; ++c) {
        unsigned long long m = __ballot(cl == c);
        if (lane == 0)
            classbit[((size_t)b * CC + c) * W32 + w0]     = (unsigned int)m;
        if (lane == 32)
            classbit[((size_t)b * CC + c) * W32 + w0 + 1] = (unsigned int)(m >> 32);
    }
}

// K1: R3-proven structure (grid (13, 512), 256 thr, lane-coalesced dwordx4,
// batched loads, branchless, fused ungated NT write) with the seg int4 stream
// replaced by the 1-bit classbit stream. Read bytes: 204.8 -> ~109 MB.
template <bool USE_BITS>
__global__ __launch_bounds__(256) void k1_main(
        const float* __restrict__ mask_logits,
        const int*   __restrict__ seg_pred,
        const unsigned int* __restrict__ classbit,
        float* __restrict__ out_mask,
        Ws* __restrict__ ws) {
    const int row = blockIdx.y;          // 0..511  (b*Q + q)
    const int b   = row >> 7;            // row / Q
    const int cls = ws->cls[row];
    const int tid = threadIdx.x;

    const f32x4* __restrict__ ml = (const f32x4*)mask_logits + (size_t)row * NV4;
    const i32x4* __restrict__ sp = (const i32x4*)seg_pred + (size_t)b * NV4;
    const unsigned int* __restrict__ cb = classbit + ((size_t)b * CC + cls) * W32;
    f32x4* __restrict__ om = (f32x4*)out_mask + (size_t)row * NV4;

    const f32x4 vz = {0.0f, 0.0f, 0.0f, 0.0f};

    int          idx[UNROLL];
    bool         act[UNROLL];
    f32x4        v[UNROLL];
    unsigned int nib[UNROLL];
    #pragma unroll
    for (int j = 0; j < UNROLL; ++j) {
        idx[j] = blockIdx.x * (TPB * UNROLL) + j * TPB + tid;  // lane-coalesced
        act[j] = idx[j] < NV4;
        v[j] = act[j] ? ml[idx[j]] : vz;
        if (USE_BITS) {
            // block/j offsets are multiples of 8 -> idx%8 == tid%8
            unsigned int cw = act[j] ? cb[idx[j] >> 3] : 0u;
            nib[j] = (cw >> ((tid & 7) * 4)) & 0xFu;
        } else {
            i32x4 ss = act[j] ? sp[idx[j]] : i32x4{-1, -1, -1, -1};
            nib[j] = ((ss.x == cls) ? 1u : 0u) | ((ss.y == cls) ? 2u : 0u)
                   | ((ss.z == cls) ? 4u : 0u) | ((ss.w == cls) ? 8u : 0u);
        }
    }

    float lsum = 0.0f;
    int   lcnt = 0;
    #pragma unroll
    for (int j = 0; j < UNROLL; ++j) {
        f32x4 vv = v[j];
        // sigmoid(x) > 0.5  <=>  x > 0
        unsigned int se = ((vv.x > 0.0f) ? 1u : 0u) | ((vv.y > 0.0f) ? 2u : 0u)
                        | ((vv.z > 0.0f) ? 4u : 0u) | ((vv.w > 0.0f) ? 8u : 0u);
        unsigned int sel = se & nib[j];
        lsum += ((sel & 1u) ? 1.0f / (1.0f + __expf(-vv.x)) : 0.0f)
              + ((sel & 2u) ? 1.0f / (1.0f + __expf(-vv.y)) : 0.0f)
              + ((sel & 4u) ? 1.0f / (1.0f + __expf(-vv.z)) : 0.0f)
              + ((sel & 8u) ? 1.0f / (1.0f + __expf(-vv.w)) : 0.0f);
        lcnt += __popc(sel);
        f32x4 o;
        o.x = (sel & 1u) ? 1.0f : 0.0f;
        o.y = (sel & 2u) ? 1.0f : 0.0f;
        o.z = (sel & 4u) ? 1.0f : 0.0f;
        o.w = (sel & 8u) ? 1.0f : 0.0f;
        if (act[j]) __builtin_nontemporal_store(o, &om[idx[j]]);
    }

    // wave64 shuffle reduce (all lanes live — no divergence above)
    #pragma unroll
    for (int off = 32; off > 0; off >>= 1) {
        lsum += __shfl_down(lsum, off);
        lcnt += __shfl_down(lcnt, off);
    }
    __shared__ float ssum[4];
    __shared__ int   scnt[4];
    const int wave = tid >> 6;
    const int lane = tid & 63;
    if (lane == 0) { ssum[wave] = lsum; scnt[wave] = lcnt; }
    __syncthreads();
    if (tid == 0) {
        atomicAdd(&ws->sum[row], ssum[0] + ssum[1] + ssum[2] + ssum[3]);
        atomicAdd(&ws->cnt[row], scnt[0] + scnt[1] + scnt[2] + scnt[3]);
    }
}

// K2: finalize per-row outputs (scores, valid, cls_pred) + global_ids copy.
__global__ void k2_finalize_gids(const int* __restrict__ fg,
                                 float* __restrict__ out,
                                 Ws* __restrict__ ws) {
    const int idx = blockIdx.x * blockDim.x + threadIdx.x;
    if (idx < ROWS) {
        int   cnt = ws->cnt[idx];
        int   cls = ws->cls[idx];
        float sum = ws->sum[idx];
        int valid = (cnt >= THRESH_CNT) && (cls >= MIN_CLS);
        ws->valid[idx] = valid;
        float* tail = out + (size_t)ROWS * NN;
        tail[idx]            = valid ? (sum / (float)max(cnt, 1)) : 0.0f;  // scores
        tail[ROWS + idx]     = valid ? 1.0f : 0.0f;                        // valid
        tail[2 * ROWS + idx] = (float)cls;                                 // cls_pred
    }
    const int nv4 = (BB * NN) / 4;   // 50000
    if (idx < nv4) {
        float* gids = out + (size_t)ROWS * NN + 3 * ROWS;
        i32x4 v = ((const i32x4*)fg)[idx];
        f32x4 o;
        o.x = (float)v.x; o.y = (float)v.y; o.z = (float)v.z; o.w = (float)v.w;
        __builtin_nontemporal_store(o, &((f32x4*)gids)[idx]);
    }
}

// K3: zero the mask rows where !valid (~20% of rows, ~20 MB of writes).
__global__ __launch_bounds__(256) void k3_fixup(
        float* __restrict__ out_mask, const Ws* __restrict__ ws) {
    const int row = blockIdx.y;
    if (ws->valid[row]) return;      // wave-uniform early exit
    f32x4* __restrict__ om = (f32x4*)out_mask + (size_t)row * NV4;
    const f32x4 z = {0.0f, 0.0f, 0.0f, 0.0f};
    const int idx0 = blockIdx.x * (TPB * UNROLL) + threadIdx.x;
    #pragma unroll
    for (int j = 0; j < UNROLL; ++j) {
        int idx = idx0 + j * TPB;
        if (idx < NV4) __builtin_nontemporal_store(z, &om[idx]);
    }
}

extern "C" void kernel_launch(void* const* d_in, const int* in_sizes, int n_in,
                              void* d_out, int out_size, void* d_ws, size_t ws_size,
                              hipStream_t stream) {
    const float* mask_logits = (const float*)d_in[0];   // [B,Q,N] f32
    const float* cls_logits  = (const float*)d_in[1];   // [B,Q,C] f32
    const int*   seg_pred    = (const int*)d_in[2];     // [B,N]   int
    const int*   fg_idxs     = (const int*)d_in[3];     // [B*N]   int

    float* out = (float*)d_out;
    Ws* ws = (Ws*)d_ws;
    unsigned int* classbit = (unsigned int*)((char*)d_ws + sizeof(Ws));

    // Output layout (flat, return order):
    //   [0, ROWS*NN)  proposal_masks | [+ROWS) scores | [+ROWS) valid
    //   [+ROWS) cls_pred | [+BB*NN) global_ids
    float* out_mask = out;

    const size_t ws_needed = sizeof(Ws)
        + (size_t)BB * CC * W32 * sizeof(unsigned int);
    const bool use_bits = (ws_size >= ws_needed);   // constant across calls

    k0_argmax_zero<<<(ROWS + 255) / 256, 256, 0, stream>>>(cls_logits, ws);

    dim3 g1(BPR, ROWS);
    const int gids_blocks = ((BB * NN) / 4 + 255) / 256;   // covers ROWS too

    if (use_bits) {
        dim3 gp((NN + TPB - 1) / TPB, BB);   // (196, 4)
        k_pre_classbit<<<gp, TPB, 0, stream>>>(seg_pred, classbit);
        k1_main<true><<<g1, TPB, 0, stream>>>(
            mask_logits, seg_pred, classbit, out_mask, ws);
    } else {
        k1_main<false><<<g1, TPB, 0, stream>>>(
            mask_logits, seg_pred, classbit, out_mask, ws);
    }

    k2_finalize_gids<<<gids_blocks, 256, 0, stream>>>(fg_idxs, out, ws);
    k3_fixup<<<g1, TPB, 0, stream>>>(out_mask, ws);
}

// Round 8
// 199.911 us; speedup vs baseline: 1.0263x; 1.0145x over previous
//
#include <hip/hip_runtime.h>
#include <math.h>

// Problem constants (GeoFormer.generate_proposal, ScanNet config)
#define BB 4
#define QQ 128
#define NN 50000
#define CC 20
#define ROWS (BB * QQ)          // 512
#define NV4 (NN / 4)            // 12500 f32x4 chunks per row
#define TPB 256
#define UNROLL 8                // 8 batched dwordx4 loads/thread (in-flight test)
#define BPR 7                   // ceil(12500 / (256*8)) blocks per row
#define W32 1568                // padded 32-bit words per row (covers 50176 bits)
#define THRESH_CNT 50
#define MIN_CLS 4

// Native clang vector types — required for __builtin_nontemporal_*
typedef float f32x4 __attribute__((ext_vector_type(4)));
typedef int   i32x4 __attribute__((ext_vector_type(4)));

// Workspace header (k0 re-inits every call; harness poisons ws with 0xAA).
// Layout: Ws | classbit[BB*CC*W32] (0.50 MB)
struct Ws {
    float sum[ROWS];
    int   cnt[ROWS];
    int   cls[ROWS];
    int   valid[ROWS];
};

// K0: per-(b,q) argmax over C=20 class logits (jnp.argmax tie-break = first
// max, i.e. strict '>' forward scan), and zero the accumulators.
__global__ void k0_argmax_zero(const float* __restrict__ cls_logits, Ws* ws) {
    int r = blockIdx.x * blockDim.x + threadIdx.x;
    if (r >= ROWS) return;
    const float* p = cls_logits + r * CC;
    float best = p[0];
    int bi = 0;
    #pragma unroll
    for (int c = 1; c < CC; ++c) {
        float v = p[c];
        if (v > best) { best = v; bi = c; }
    }
    ws->cls[r] = bi;
    ws->sum[r] = 0.0f;
    ws->cnt[r] = 0;
}

// K_PRE: per-class point bitmask classbit[b][c][w]: bit (p%32) of word p/32 =
// (seg_pred[b][p] == c). 0.5 MB, L2/L3-resident; k1 reads 1 bit/element.
__global__ void k_pre_classbit(const int* __restrict__ seg,
                               unsigned int* __restrict__ classbit) {
    const int b = blockIdx.y;
    const int p = blockIdx.x * TPB + threadIdx.x;     // point id
    const int lane = threadIdx.x & 63;
    const int cl = (p < NN) ? seg[b * NN + p] : -1;
    // first 32-bit word of this wave's 64-point span
    const int w0 = (blockIdx.x * TPB + (threadIdx.x & ~63)) >> 5;
    #pragma unroll
    for (int c = 0; c < CC; ++c) {
        unsigned long long m = __ballot(cl == c);
        if (lane == 0)
            classbit[((size_t)b * CC + c) * W32 + w0]     = (unsigned int)m;
        if (lane == 32)
            classbit[((size_t)b * CC + c) * W32 + w0 + 1] = (unsigned int)(m >> 32);
    }
}

// K1: R7 structure with 2x the in-flight mask bytes per wave (UNROLL=8,
// all 8 dwordx4 loads batched before use; NT loads keep the single-use mask
// stream from evicting L2-resident classbit). Discriminates inflight-cap vs
// L2-miss-fill-cap models.
template <bool USE_BITS>
__global__ __launch_bounds__(256) void k1_main(
        const float* __restrict__ mask_logits,
        const int*   __restrict__ seg_pred,
        const unsigned int* __restrict__ classbit,
        float* __restrict__ out_mask,
        Ws* __restrict__ ws) {
    const int row = blockIdx.y;          // 0..511  (b*Q + q)
    const int b   = row >> 7;            // row / Q
    const int cls = ws->cls[row];
    const int tid = threadIdx.x;

    const f32x4* __restrict__ ml = (const f32x4*)mask_logits + (size_t)row * NV4;
    const i32x4* __restrict__ sp = (const i32x4*)seg_pred + (size_t)b * NV4;
    const unsigned int* __restrict__ cb = classbit + ((size_t)b * CC + cls) * W32;
    f32x4* __restrict__ om = (f32x4*)out_mask + (size_t)row * NV4;

    const f32x4 vz = {0.0f, 0.0f, 0.0f, 0.0f};

    int          idx[UNROLL];
    bool         act[UNROLL];
    f32x4        v[UNROLL];
    unsigned int nib[UNROLL];
    #pragma unroll
    for (int j = 0; j < UNROLL; ++j) {
        idx[j] = blockIdx.x * (TPB * UNROLL) + j * TPB + tid;  // lane-coalesced
        act[j] = idx[j] < NV4;
        v[j] = act[j] ? __builtin_nontemporal_load(&ml[idx[j]]) : vz;
        if (USE_BITS) {
            // block/j offsets are multiples of 8 -> idx%8 == tid%8
            unsigned int cw = act[j] ? cb[idx[j] >> 3] : 0u;
            nib[j] = (cw >> ((tid & 7) * 4)) & 0xFu;
        } else {
            i32x4 ss = act[j] ? sp[idx[j]] : i32x4{-1, -1, -1, -1};
            nib[j] = ((ss.x == cls) ? 1u : 0u) | ((ss.y == cls) ? 2u : 0u)
                   | ((ss.z == cls) ? 4u : 0u) | ((ss.w == cls) ? 8u : 0u);
        }
    }

    float lsum = 0.0f;
    int   lcnt = 0;
    #pragma unroll
    for (int j = 0; j < UNROLL; ++j) {
        f32x4 vv = v[j];
        // sigmoid(x) > 0.5  <=>  x > 0
        unsigned int se = ((vv.x > 0.0f) ? 1u : 0u) | ((vv.y > 0.0f) ? 2u : 0u)
                        | ((vv.z > 0.0f) ? 4u : 0u) | ((vv.w > 0.0f) ? 8u : 0u);
        unsigned int sel = se & nib[j];
        lsum += ((sel & 1u) ? 1.0f / (1.0f + __expf(-vv.x)) : 0.0f)
              + ((sel & 2u) ? 1.0f / (1.0f + __expf(-vv.y)) : 0.0f)
              + ((sel & 4u) ? 1.0f / (1.0f + __expf(-vv.z)) : 0.0f)
              + ((sel & 8u) ? 1.0f / (1.0f + __expf(-vv.w)) : 0.0f);
        lcnt += __popc(sel);
        f32x4 o;
        o.x = (sel & 1u) ? 1.0f : 0.0f;
        o.y = (sel & 2u) ? 1.0f : 0.0f;
        o.z = (sel & 4u) ? 1.0f : 0.0f;
        o.w = (sel & 8u) ? 1.0f : 0.0f;
        if (act[j]) __builtin_nontemporal_store(o, &om[idx[j]]);
    }

    // wave64 shuffle reduce (all lanes live — no divergence above)
    #pragma unroll
    for (int off = 32; off > 0; off >>= 1) {
        lsum += __shfl_down(lsum, off);
        lcnt += __shfl_down(lcnt, off);
    }
    __shared__ float ssum[4];
    __shared__ int   scnt[4];
    const int wave = tid >> 6;
    const int lane = tid & 63;
    if (lane == 0) { ssum[wave] = lsum; scnt[wave] = lcnt; }
    __syncthreads();
    if (tid == 0) {
        atomicAdd(&ws->sum[row], ssum[0] + ssum[1] + ssum[2] + ssum[3]);
        atomicAdd(&ws->cnt[row], scnt[0] + scnt[1] + scnt[2] + scnt[3]);
    }
}

// K2: finalize per-row outputs (scores, valid, cls_pred) + global_ids copy.
__global__ void k2_finalize_gids(const int* __restrict__ fg,
                                 float* __restrict__ out,
                                 Ws* __restrict__ ws) {
    const int idx = blockIdx.x * blockDim.x + threadIdx.x;
    if (idx < ROWS) {
        int   cnt = ws->cnt[idx];
        int   cls = ws->cls[idx];
        float sum = ws->sum[idx];
        int valid = (cnt >= THRESH_CNT) && (cls >= MIN_CLS);
        ws->valid[idx] = valid;
        float* tail = out + (size_t)ROWS * NN;
        tail[idx]            = valid ? (sum / (float)max(cnt, 1)) : 0.0f;  // scores
        tail[ROWS + idx]     = valid ? 1.0f : 0.0f;                        // valid
        tail[2 * ROWS + idx] = (float)cls;                                 // cls_pred
    }
    const int nv4 = (BB * NN) / 4;   // 50000
    if (idx < nv4) {
        float* gids = out + (size_t)ROWS * NN + 3 * ROWS;
        i32x4 v = ((const i32x4*)fg)[idx];
        f32x4 o;
        o.x = (float)v.x; o.y = (float)v.y; o.z = (float)v.z; o.w = (float)v.w;
        __builtin_nontemporal_store(o, &((f32x4*)gids)[idx]);
    }
}

// K3: zero the mask rows where !valid (~20% of rows, ~20 MB of writes).
__global__ __launch_bounds__(256) void k3_fixup(
        float* __restrict__ out_mask, const Ws* __restrict__ ws) {
    const int row = blockIdx.y;
    if (ws->valid[row]) return;      // wave-uniform early exit
    f32x4* __restrict__ om = (f32x4*)out_mask + (size_t)row * NV4;
    const f32x4 z = {0.0f, 0.0f, 0.0f, 0.0f};
    const int idx0 = blockIdx.x * (TPB * UNROLL) + threadIdx.x;
    #pragma unroll
    for (int j = 0; j < UNROLL; ++j) {
        int idx = idx0 + j * TPB;
        if (idx < NV4) __builtin_nontemporal_store(z, &om[idx]);
    }
}

extern "C" void kernel_launch(void* const* d_in, const int* in_sizes, int n_in,
                              void* d_out, int out_size, void* d_ws, size_t ws_size,
                              hipStream_t stream) {
    const float* mask_logits = (const float*)d_in[0];   // [B,Q,N] f32
    const float* cls_logits  = (const float*)d_in[1];   // [B,Q,C] f32
    const int*   seg_pred    = (const int*)d_in[2];     // [B,N]   int
    const int*   fg_idxs     = (const int*)d_in[3];     // [B*N]   int

    float* out = (float*)d_out;
    Ws* ws = (Ws*)d_ws;
    unsigned int* classbit = (unsigned int*)((char*)d_ws + sizeof(Ws));

    // Output layout (flat, return order):
    //   [0, ROWS*NN)  proposal_masks | [+ROWS) scores | [+ROWS) valid
    //   [+ROWS) cls_pred | [+BB*NN) global_ids
    float* out_mask = out;

    const size_t ws_needed = sizeof(Ws)
        + (size_t)BB * CC * W32 * sizeof(unsigned int);
    const bool use_bits = (ws_size >= ws_needed);   // constant across calls

    k0_argmax_zero<<<(ROWS + 255) / 256, 256, 0, stream>>>(cls_logits, ws);

    dim3 g1(BPR, ROWS);
    const int gids_blocks = ((BB * NN) / 4 + 255) / 256;   // covers ROWS too

    if (use_bits) {
        dim3 gp((NN + TPB - 1) / TPB, BB);   // (196, 4)
        k_pre_classbit<<<gp, TPB, 0, stream>>>(seg_pred, classbit);
        k1_main<true><<<g1, TPB, 0, stream>>>(
            mask_logits, seg_pred, classbit, out_mask, ws);
    } else {
        k1_main<false><<<g1, TPB, 0, stream>>>(
            mask_logits, seg_pred, classbit, out_mask, ws);
    }

    k2_finalize_gids<<<gids_blocks, 256, 0, stream>>>(fg_idxs, out, ws);
    k3_fixup<<<g1, TPB, 0, stream>>>(out_mask, ws);
}